// Round 1
// baseline (529.170 us; speedup 1.0000x reference)
//
#include <hip/hip_runtime.h>
#include <stdint.h>

#define N_TOK 6144
#define DMODEL 768
#define NHEAD 3
#define DHEAD 256
#define NWORDS (N_TOK/32)  // 192 mask words per row

typedef __bf16 bf16x8 __attribute__((ext_vector_type(8)));
typedef float f32x4 __attribute__((ext_vector_type(4)));
typedef unsigned short u16;
typedef u16 u16x8 __attribute__((ext_vector_type(8)));
typedef u16 u16x4 __attribute__((ext_vector_type(4)));
typedef unsigned int u32;

__device__ __forceinline__ u16 f2bf(float f) {
  union { float f; u32 u; } v; v.f = f;
  u32 u = v.u;
  u32 r = (u + 0x7FFFu + ((u >> 16) & 1u)) >> 16;  // RNE
  return (u16)r;
}
__device__ __forceinline__ float lrelu(float v) { return v >= 0.f ? v : 0.2f * v; }

// ---------------- adj [N][N] int32 -> bitmask [N][NWORDS] ----------------
__global__ __launch_bounds__(256) void pack_adj(const int* __restrict__ adj,
                                                u32* __restrict__ bits) {
  size_t wid = (size_t)blockIdx.x * 256 + threadIdx.x;   // one 32-key word
  const int4* p = reinterpret_cast<const int4*>(adj + wid * 32);
  u32 m = 0;
#pragma unroll
  for (int i = 0; i < 8; ++i) {
    int4 v = p[i];
    m |= (v.x != 0 ? 1u : 0u) << (i * 4 + 0);
    m |= (v.y != 0 ? 1u : 0u) << (i * 4 + 1);
    m |= (v.z != 0 ? 1u : 0u) << (i * 4 + 2);
    m |= (v.w != 0 ? 1u : 0u) << (i * 4 + 3);
  }
  bits[wid] = m;
}

// ---------------- bf16 transpose: src[N][768] -> dst[768][N] ----------------
__global__ __launch_bounds__(256) void transpose_bf(const u16* __restrict__ src,
                                                    u16* __restrict__ dst) {
  __shared__ u16 t[64][72];
  const int n0 = blockIdx.x * 64, d0 = blockIdx.y * 64;
  const int tid = threadIdx.x;
#pragma unroll
  for (int i = 0; i < 2; ++i) {
    int c = tid + i * 256;
    int r = c >> 3, c8 = (c & 7) * 8;
    *reinterpret_cast<u16x8*>(&t[r][c8]) =
        *reinterpret_cast<const u16x8*>(src + (size_t)(n0 + r) * DMODEL + d0 + c8);
  }
  __syncthreads();
#pragma unroll
  for (int i = 0; i < 2; ++i) {
    int c = tid + i * 256;
    int dr = c >> 3, n8 = (c & 7) * 8;
    u16x8 v;
#pragma unroll
    for (int j = 0; j < 8; ++j) v[j] = t[n8 + j][dr];
    *reinterpret_cast<u16x8*>(dst + (size_t)(d0 + dr) * N_TOK + n0 + n8) = v;
  }
}

// ---------------- NT GEMM: C[6144,768] = A[6144,768] @ W[768,768]^T ----------------
// ABF: A is bf16 (else f32, converted during staging). FINAL: out_f = resid + lrelu(acc+b),
// else out_bf = bf16(lrelu(acc+b)).
template <int ABF, int FINAL>
__global__ __launch_bounds__(256) void gemm_nt(const void* __restrict__ Aptr,
                                               const float* __restrict__ W,
                                               const float* __restrict__ bias,
                                               const float* __restrict__ resid,
                                               u16* __restrict__ out_bf,
                                               float* __restrict__ out_f) {
  __shared__ u16 As[128][72];
  __shared__ u16 Bs[128][72];
  const int tid = threadIdx.x;
  const int w = tid >> 6, lane = tid & 63, lr = lane & 15, lg = lane >> 4;
  const int m0 = blockIdx.x * 128, n0 = blockIdx.y * 128;
  const int wr = (w >> 1) * 64, wc = (w & 1) * 64;
  f32x4 acc[4][4] = {};
  for (int kt = 0; kt < DMODEL / 64; ++kt) {
    __syncthreads();
#pragma unroll
    for (int i = 0; i < 4; ++i) {
      int c = tid + i * 256;
      int row = c >> 3, c8 = (c & 7) * 8;
      int gcol = kt * 64 + c8;
      if (ABF) {
        *reinterpret_cast<u16x8*>(&As[row][c8]) = *reinterpret_cast<const u16x8*>(
            (const u16*)Aptr + (size_t)(m0 + row) * DMODEL + gcol);
      } else {
        const float* src = (const float*)Aptr + (size_t)(m0 + row) * DMODEL + gcol;
        float4 f0 = *reinterpret_cast<const float4*>(src);
        float4 f1 = *reinterpret_cast<const float4*>(src + 4);
        u16x8 v = {f2bf(f0.x), f2bf(f0.y), f2bf(f0.z), f2bf(f0.w),
                   f2bf(f1.x), f2bf(f1.y), f2bf(f1.z), f2bf(f1.w)};
        *reinterpret_cast<u16x8*>(&As[row][c8]) = v;
      }
      const float* wsrc = W + (size_t)(n0 + row) * DMODEL + gcol;
      float4 g0 = *reinterpret_cast<const float4*>(wsrc);
      float4 g1 = *reinterpret_cast<const float4*>(wsrc + 4);
      u16x8 wv = {f2bf(g0.x), f2bf(g0.y), f2bf(g0.z), f2bf(g0.w),
                  f2bf(g1.x), f2bf(g1.y), f2bf(g1.z), f2bf(g1.w)};
      *reinterpret_cast<u16x8*>(&Bs[row][c8]) = wv;
    }
    __syncthreads();
#pragma unroll
    for (int ks = 0; ks < 2; ++ks) {
      bf16x8 a[4], b[4];
#pragma unroll
      for (int mi = 0; mi < 4; ++mi)
        a[mi] = *reinterpret_cast<const bf16x8*>(&As[wr + mi * 16 + lr][ks * 32 + lg * 8]);
#pragma unroll
      for (int ni = 0; ni < 4; ++ni)
        b[ni] = *reinterpret_cast<const bf16x8*>(&Bs[wc + ni * 16 + lr][ks * 32 + lg * 8]);
#pragma unroll
      for (int mi = 0; mi < 4; ++mi)
#pragma unroll
        for (int ni = 0; ni < 4; ++ni)
          acc[mi][ni] =
              __builtin_amdgcn_mfma_f32_16x16x32_bf16(a[mi], b[ni], acc[mi][ni], 0, 0, 0);
    }
  }
#pragma unroll
  for (int mi = 0; mi < 4; ++mi)
#pragma unroll
    for (int ni = 0; ni < 4; ++ni)
#pragma unroll
      for (int r = 0; r < 4; ++r) {
        int grow = m0 + wr + mi * 16 + lg * 4 + r;
        int gcol = n0 + wc + ni * 16 + lr;
        float v = lrelu(acc[mi][ni][r] + bias[gcol]);
        size_t idx = (size_t)grow * DMODEL + gcol;
        if (FINAL)
          out_f[idx] = resid[idx] + v;
        else
          out_bf[idx] = f2bf(v);
      }
}

// ---------------- fused masked flash attention, all 3 heads via blockIdx.y ----------------
// block: 256 thr = 4 waves, each wave owns 16 q-rows. K-tile = 32 keys.
__global__ __launch_bounds__(256) void attn_fused(
    const u16* __restrict__ Kmat,  // x_new bf16 [N][768]
    const u16* __restrict__ Qmat,  // q bf16 [N][768]
    const u16* __restrict__ VT,    // x_new^T bf16 [768][N]
    const u32* __restrict__ bits,  // [N][NWORDS]
    const float* __restrict__ x,   // residual [N][768] f32
    u16* __restrict__ out2) {      // bf16 [N][768]  (= x + attn)
  __shared__ u16 Ks[32][264];   // [key][dh]  pad -> balanced banks
  __shared__ u16 Vs[256][40];   // [dh][key]
  __shared__ u16 Ps[4][16][40]; // per-wave [q][key]
  __shared__ u32 adjw[64];
  const int tid = threadIdx.x;
  const int w = tid >> 6, lane = tid & 63, lr = lane & 15, lg = lane >> 4;
  const int q0 = blockIdx.x * 64;
  const int h = blockIdx.y;

  // Q fragments in registers: lane holds q-row (w*16+lr), dh = s*32 + lg*8 .. +7
  bf16x8 qf[8];
  {
    const u16* qrow = Qmat + (size_t)(q0 + w * 16 + lr) * DMODEL + h * DHEAD + lg * 8;
#pragma unroll
    for (int s = 0; s < 8; ++s)
      qf[s] = *reinterpret_cast<const bf16x8*>(qrow + s * 32);
  }
  f32x4 o[16] = {};
  float m = -1e30f, lsum = 0.f;

  for (int kt = 0; kt < N_TOK / 32; ++kt) {
    __syncthreads();
#pragma unroll
    for (int i = 0; i < 4; ++i) {
      int c = tid + i * 256;
      {  // K tile 32x256
        int kr = c >> 5, c8 = (c & 31) * 8;
        *reinterpret_cast<u16x8*>(&Ks[kr][c8]) = *reinterpret_cast<const u16x8*>(
            Kmat + (size_t)(kt * 32 + kr) * DMODEL + h * DHEAD + c8);
      }
      {  // V^T tile 256x32
        int dr = c >> 2, c8 = (c & 3) * 8;
        *reinterpret_cast<u16x8*>(&Vs[dr][c8]) = *reinterpret_cast<const u16x8*>(
            VT + (size_t)(h * DHEAD + dr) * N_TOK + kt * 32 + c8);
      }
    }
    if (tid < 64) adjw[tid] = bits[(size_t)(q0 + tid) * NWORDS + kt];
    __syncthreads();

    // S^T[key, q] = K_tile @ Q^T  (swapped -> lane owns q = lr)
    f32x4 st[2] = {};
#pragma unroll
    for (int s = 0; s < 8; ++s) {
      bf16x8 k0 = *reinterpret_cast<const bf16x8*>(&Ks[lr][s * 32 + lg * 8]);
      bf16x8 k1 = *reinterpret_cast<const bf16x8*>(&Ks[16 + lr][s * 32 + lg * 8]);
      st[0] = __builtin_amdgcn_mfma_f32_16x16x32_bf16(k0, qf[s], st[0], 0, 0, 0);
      st[1] = __builtin_amdgcn_mfma_f32_16x16x32_bf16(k1, qf[s], st[1], 0, 0, 0);
    }
    const u32 word = adjw[w * 16 + lr];
    float pv[2][4];
    float tmax = -1e30f;
#pragma unroll
    for (int kb = 0; kb < 2; ++kb)
#pragma unroll
      for (int r = 0; r < 4; ++r) {
        int keyl = kb * 16 + lg * 4 + r;
        float sv = ((word >> keyl) & 1u) ? st[kb][r] * 0.1f : -1e30f;
        pv[kb][r] = sv;
        tmax = fmaxf(tmax, sv);
      }
    tmax = fmaxf(tmax, __shfl_xor(tmax, 16));
    tmax = fmaxf(tmax, __shfl_xor(tmax, 32));
    float mnew = fmaxf(m, tmax);
    float alpha = __expf(m - mnew);  // both -1e30 -> exp(0)=1; garbage self-corrects
    float rsum = 0.f;
#pragma unroll
    for (int kb = 0; kb < 2; ++kb) {
      u16x4 pk;
#pragma unroll
      for (int r = 0; r < 4; ++r) {
        float p = __expf(pv[kb][r] - mnew);
        rsum += p;
        pk[r] = f2bf(p);
      }
      *reinterpret_cast<u16x4*>(&Ps[w][lr][kb * 16 + lg * 4]) = pk;
    }
    rsum += __shfl_xor(rsum, 16);
    rsum += __shfl_xor(rsum, 32);
    lsum = lsum * alpha + rsum;
    m = mnew;
    // alpha per O-row (row = lg*4+r); source lane lg*4+r owns that q
    float ar[4];
#pragma unroll
    for (int r = 0; r < 4; ++r) ar[r] = __shfl(alpha, lg * 4 + r);
#pragma unroll
    for (int d = 0; d < 16; ++d) {
      o[d][0] *= ar[0]; o[d][1] *= ar[1]; o[d][2] *= ar[2]; o[d][3] *= ar[3];
    }
    // cross-lane P exchange goes through LDS: force write completion
    asm volatile("s_waitcnt lgkmcnt(0)" ::: "memory");
    bf16x8 pf = *reinterpret_cast<const bf16x8*>(&Ps[w][lr][lg * 8]);
#pragma unroll
    for (int d = 0; d < 16; ++d) {
      bf16x8 vf = *reinterpret_cast<const bf16x8*>(&Vs[d * 16 + lr][lg * 8]);
      o[d] = __builtin_amdgcn_mfma_f32_16x16x32_bf16(pf, vf, o[d], 0, 0, 0);
    }
  }
  // epilogue: O/l, add residual x, store bf16
  float ls[4];
#pragma unroll
  for (int r = 0; r < 4; ++r) ls[r] = __shfl(lsum, lg * 4 + r);
#pragma unroll
  for (int d = 0; d < 16; ++d)
#pragma unroll
    for (int r = 0; r < 4; ++r) {
      int grow = q0 + w * 16 + lg * 4 + r;
      int gcol = h * DHEAD + d * 16 + lr;
      size_t idx = (size_t)grow * DMODEL + gcol;
      out2[idx] = f2bf(x[idx] + o[d][r] / ls[r]);
    }
}

extern "C" void kernel_launch(void* const* d_in, const int* in_sizes, int n_in,
                              void* d_out, int out_size, void* d_ws, size_t ws_size,
                              hipStream_t stream) {
  const float* x     = (const float*)d_in[0];
  const int*   adj   = (const int*)d_in[1];
  const float* W_fc  = (const float*)d_in[2];
  const float* b_fc  = (const float*)d_in[3];
  const float* W_qfc = (const float*)d_in[4];
  const float* b_qfc = (const float*)d_in[5];
  const float* W_fin = (const float*)d_in[6];
  const float* b_fin = (const float*)d_in[7];
  float* out = (float*)d_out;

  char* ws = (char*)d_ws;
  size_t off = 0;
  auto alloc = [&](size_t bytes) {
    char* p = ws + off;
    off += (bytes + 255) & ~(size_t)255;
    return p;
  };
  u16* xnew_bf = (u16*)alloc((size_t)N_TOK * DMODEL * 2);
  u16* q_bf    = (u16*)alloc((size_t)N_TOK * DMODEL * 2);
  u16* xT      = (u16*)alloc((size_t)DMODEL * N_TOK * 2);
  u16* out2_bf = (u16*)alloc((size_t)N_TOK * DMODEL * 2);
  u32* bits    = (u32*)alloc((size_t)N_TOK * NWORDS * 4);

  pack_adj<<<N_TOK * NWORDS / 256, 256, 0, stream>>>(adj, bits);
  dim3 ggrid(N_TOK / 128, DMODEL / 128);
  gemm_nt<0, 0><<<ggrid, 256, 0, stream>>>(x, W_fc, b_fc, nullptr, xnew_bf, nullptr);
  gemm_nt<1, 0><<<ggrid, 256, 0, stream>>>(xnew_bf, W_qfc, b_qfc, nullptr, q_bf, nullptr);
  transpose_bf<<<dim3(N_TOK / 64, DMODEL / 64), 256, 0, stream>>>(xnew_bf, xT);
  attn_fused<<<dim3(N_TOK / 64, NHEAD), 256, 0, stream>>>(xnew_bf, q_bf, xT, bits, x, out2_bf);
  gemm_nt<1, 1><<<ggrid, 256, 0, stream>>>(out2_bf, W_fin, b_fin, x, nullptr, out);
}